// Round 1
// baseline (141.582 us; speedup 1.0000x reference)
//
#include <hip/hip_runtime.h>
#include <math.h>

// Sizes from the reference
#define B_SZ 4096
#define N_SZ 16
#define A_SZ 8
#define IN_DIM 128
#define OUT_DIM 128
#define D_OBS 128
#define ROW_OUT (D_OBS + A_SZ)   // 136

// ---------------------------------------------------------------------------
// Kernel 1: fold W_attn into W_fc.
//   v_src[i] = sum_o W_fc[o,i] * W_attn[0,o]
//   v_dst[i] = sum_o W_fc[o,i] * W_attn[0,128+o]
// 1 block, 128 threads. Reads 64 KB, trivial.
// ---------------------------------------------------------------------------
__global__ void prep_v(const float* __restrict__ W_fc,
                       const float* __restrict__ W_attn,
                       float* __restrict__ v) {
  const int i = threadIdx.x;  // 0..127
  float s = 0.f, d = 0.f;
  for (int o = 0; o < OUT_DIM; ++o) {
    const float w = W_fc[o * IN_DIM + i];
    s += w * W_attn[o];
    d += w * W_attn[OUT_DIM + o];
  }
  v[i] = s;
  v[IN_DIM + i] = d;
}

// ---------------------------------------------------------------------------
// Kernel 2: one block per batch element b. 256 threads (4 waves).
// ---------------------------------------------------------------------------
__global__ __launch_bounds__(256) void gat_main(
    const float* __restrict__ h,        // [B,16,128]
    const float* __restrict__ pol,      // [B,16,8]
    const float* __restrict__ act,      // [B,16,8]
    const float* __restrict__ obs,      // [B*16,128]
    const float* __restrict__ v,        // [256] (v_src | v_dst)
    float* __restrict__ out_obs,        // [B*16,16,136]
    float* __restrict__ out_w)          // [B*16,16,1]
{
  const int b = blockIdx.x;
  const int tid = threadIdx.x;

  __shared__ float a_src_sm[16];
  __shared__ float a_dst_sm[16];
  __shared__ float w_sm[256];        // [i][j]
  __shared__ float pol_sm[128];      // [j][a]
  __shared__ float act_sm[128];
  __shared__ float sumz_sm[128];     // [i][a]
  __shared__ float outz_sm[2048];    // [i][k][a]
  __shared__ float obs_sm[2048];     // [k][d]

  // --- stage obs tile (16x128 = 512 float4) ---
  {
    const float4* op = (const float4*)(obs + (size_t)b * (N_SZ * D_OBS));
    float4* od = (float4*)obs_sm;
    od[tid]       = op[tid];
    od[tid + 256] = op[tid + 256];
  }
  // --- stage policies / actions (128 floats each) ---
  if (tid < 128) {
    pol_sm[tid] = pol[(size_t)b * (N_SZ * A_SZ) + tid];
    act_sm[tid] = act[(size_t)b * (N_SZ * A_SZ) + tid];
  }

  // --- phase 1: a_src/a_dst. 16 lanes per row, 8 elems per lane. ---
  {
    const int n = tid >> 4;       // row 0..15
    const int l = tid & 15;       // lane-in-row
    // h elements tid*8 .. tid*8+7  (fully contiguous across the block)
    const float4* hp = (const float4*)(h + (size_t)b * (N_SZ * IN_DIM));
    const float4 h0 = hp[tid * 2];
    const float4 h1 = hp[tid * 2 + 1];
    const float4* vs = (const float4*)v;
    const float4* vd = (const float4*)(v + IN_DIM);
    const float4 s0 = vs[l * 2], s1 = vs[l * 2 + 1];
    const float4 d0 = vd[l * 2], d1 = vd[l * 2 + 1];
    float s = h0.x * s0.x + h0.y * s0.y + h0.z * s0.z + h0.w * s0.w
            + h1.x * s1.x + h1.y * s1.y + h1.z * s1.z + h1.w * s1.w;
    float d = h0.x * d0.x + h0.y * d0.y + h0.z * d0.z + h0.w * d0.w
            + h1.x * d1.x + h1.y * d1.y + h1.z * d1.z + h1.w * d1.w;
    // reduce across the 16 lanes of this row
    for (int m = 8; m >= 1; m >>= 1) {
      s += __shfl_xor(s, m, 16);
      d += __shfl_xor(d, m, 16);
    }
    if (l == 0) {
      a_src_sm[n] = s;
      a_dst_sm[n] = d;
    }
  }
  __syncthreads();

  // --- phase 2: w[i][j] = sigmoid(leaky_relu(a_src[j] + a_dst[i], 0.01)) ---
  {
    const int i = tid >> 4, j = tid & 15;
    float e = a_src_sm[j] + a_dst_sm[i];
    e = (e >= 0.f) ? e : 0.01f * e;
    const float wv = 1.f / (1.f + expf(-e));
    w_sm[tid] = wv;
    out_w[(size_t)b * 256 + tid] = wv;   // output 1, coalesced
  }
  __syncthreads();

  // --- phase 3a: sum_z[i][a] = sum_j (w[i][j]*act[j][a] + (1-w)*pol[j][a]) ---
  if (tid < 128) {
    const int i = tid >> 3, a = tid & 7;
    float s = 0.f;
    for (int j = 0; j < N_SZ; ++j) {
      const float wv = w_sm[i * 16 + j];
      s += wv * act_sm[j * 8 + a] + (1.f - wv) * pol_sm[j * 8 + a];
    }
    sumz_sm[tid] = s;
  }
  __syncthreads();

  // --- phase 3b: out_z[i][k][a] = (sum_z[i][a] - zg[i][k][a] + pol[k][a])/16 ---
  {
    const int i = tid >> 4, k = tid & 15;
    const float wv = w_sm[tid];   // w[i][k]
    for (int a = 0; a < A_SZ; ++a) {
      const float zg = wv * act_sm[k * 8 + a] + (1.f - wv) * pol_sm[k * 8 + a];
      outz_sm[tid * 8 + a] =
          (sumz_sm[i * 8 + a] - zg + pol_sm[k * 8 + a]) * 0.0625f;
    }
  }
  __syncthreads();

  // --- phase 4: write 256 rows x 34 float4 (fully contiguous per block) ---
  // flat float4 idx: r = i*16+k = idx/34, d4 = idx%34.
  // d4 < 32  -> obs_sm[k][d4*4 ..]
  // d4 >= 32 -> outz_sm[r*8 + (d4-32)*4 ..]
  float* ob = out_obs + (size_t)b * (256 * ROW_OUT);
  const float4* obs4 = (const float4*)obs_sm;
  #pragma unroll 2
  for (int idx = tid; idx < 256 * 34; idx += 256) {
    const int r = idx / 34;
    const int d4 = idx - r * 34;
    float4 o4;
    if (d4 < 32) {
      const int k = r & 15;
      o4 = obs4[k * 32 + d4];
    } else {
      o4 = *(const float4*)(outz_sm + r * 8 + (d4 - 32) * 4);
    }
    *(float4*)(ob + (size_t)idx * 4) = o4;   // row stride 136 = 34*4 floats
  }
}

// ---------------------------------------------------------------------------
extern "C" void kernel_launch(void* const* d_in, const int* in_sizes, int n_in,
                              void* d_out, int out_size, void* d_ws, size_t ws_size,
                              hipStream_t stream) {
  const float* h      = (const float*)d_in[0];
  const float* pol    = (const float*)d_in[1];
  const float* act    = (const float*)d_in[2];
  const float* obs    = (const float*)d_in[3];
  const float* W_fc   = (const float*)d_in[4];
  const float* W_attn = (const float*)d_in[5];

  float* out = (float*)d_out;
  float* out_w = out + (size_t)B_SZ * N_SZ * N_SZ * ROW_OUT;  // 142,606,336
  float* v = (float*)d_ws;  // 256 floats

  prep_v<<<1, 128, 0, stream>>>(W_fc, W_attn, v);
  gat_main<<<B_SZ, 256, 0, stream>>>(h, pol, act, obs, v, out, out_w);
}

// Round 3
// 137.772 us; speedup vs baseline: 1.0277x; 1.0277x over previous
//
#include <hip/hip_runtime.h>
#include <math.h>

// Sizes from the reference
#define B_SZ 4096
#define N_SZ 16
#define A_SZ 8
#define IN_DIM 128
#define OUT_DIM 128
#define D_OBS 128
#define ROW_OUT (D_OBS + A_SZ)   // 136

// Native clang vector (required by __builtin_nontemporal_*; HIP float4 is a struct)
typedef float f32x4 __attribute__((ext_vector_type(4)));

// ---------------------------------------------------------------------------
// Kernel 1: fold W_attn into W_fc.
//   v_src[i] = sum_o W_fc[o,i] * W_attn[0,o]
//   v_dst[i] = sum_o W_fc[o,i] * W_attn[0,128+o]
// 1 block, 256 threads, split-K by 2 to cut latency of the serial dispatch.
// ---------------------------------------------------------------------------
__global__ __launch_bounds__(256) void prep_v(const float* __restrict__ W_fc,
                                              const float* __restrict__ W_attn,
                                              float* __restrict__ v) {
  __shared__ float part[2][2][128];  // [half][src/dst][i]
  const int i = threadIdx.x & 127;
  const int half = threadIdx.x >> 7;   // 0: o in [0,64), 1: o in [64,128)
  float s = 0.f, d = 0.f;
  #pragma unroll 8
  for (int oo = 0; oo < 64; ++oo) {
    const int o = half * 64 + oo;
    const float w = W_fc[o * IN_DIM + i];
    s += w * W_attn[o];
    d += w * W_attn[OUT_DIM + o];
  }
  part[half][0][i] = s;
  part[half][1][i] = d;
  __syncthreads();
  if (half == 0) {
    v[i]          = part[0][0][i] + part[1][0][i];
    v[IN_DIM + i] = part[0][1][i] + part[1][1][i];
  }
}

// ---------------------------------------------------------------------------
// Kernel 2: one block per batch element b. 256 threads (4 waves).
// All global traffic is touch-once -> non-temporal loads/stores throughout.
// ---------------------------------------------------------------------------
__global__ __launch_bounds__(256) void gat_main(
    const float* __restrict__ h,        // [B,16,128]
    const float* __restrict__ pol,      // [B,16,8]
    const float* __restrict__ act,      // [B,16,8]
    const float* __restrict__ obs,      // [B*16,128]
    const float* __restrict__ v,        // [256] (v_src | v_dst)
    float* __restrict__ out_obs,        // [B*16,16,136]
    float* __restrict__ out_w)          // [B*16,16,1]
{
  const int b = blockIdx.x;
  const int tid = threadIdx.x;

  __shared__ float a_src_sm[16];
  __shared__ float a_dst_sm[16];
  __shared__ float w_sm[256];        // [i][j]
  __shared__ float pol_sm[128];      // [j][a]
  __shared__ float act_sm[128];
  __shared__ float sumz_sm[128];     // [i][a]
  __shared__ float outz_sm[2048];    // [i][k][a]
  __shared__ float obs_sm[2048];     // [k][d]

  // --- stage obs tile (16x128 = 512 x 16B), streaming loads ---
  {
    const f32x4* op = (const f32x4*)(obs + (size_t)b * (N_SZ * D_OBS));
    f32x4* od = (f32x4*)obs_sm;
    od[tid]       = __builtin_nontemporal_load(&op[tid]);
    od[tid + 256] = __builtin_nontemporal_load(&op[tid + 256]);
  }
  // --- stage policies / actions (128 floats each) ---
  if (tid < 128) {
    pol_sm[tid] = __builtin_nontemporal_load(&pol[(size_t)b * (N_SZ * A_SZ) + tid]);
    act_sm[tid] = __builtin_nontemporal_load(&act[(size_t)b * (N_SZ * A_SZ) + tid]);
  }

  // --- phase 1: a_src/a_dst. 16 lanes per row, 8 elems per lane. ---
  {
    const int n = tid >> 4;       // row 0..15
    const int l = tid & 15;       // lane-in-row
    const f32x4* hp = (const f32x4*)(h + (size_t)b * (N_SZ * IN_DIM));
    const f32x4 h0 = __builtin_nontemporal_load(&hp[tid * 2]);
    const f32x4 h1 = __builtin_nontemporal_load(&hp[tid * 2 + 1]);
    const f32x4* vs = (const f32x4*)v;
    const f32x4* vd = (const f32x4*)(v + IN_DIM);
    const f32x4 s0 = vs[l * 2], s1 = vs[l * 2 + 1];   // v: hot, keep cached
    const f32x4 d0 = vd[l * 2], d1 = vd[l * 2 + 1];
    float s = h0.x * s0.x + h0.y * s0.y + h0.z * s0.z + h0.w * s0.w
            + h1.x * s1.x + h1.y * s1.y + h1.z * s1.z + h1.w * s1.w;
    float d = h0.x * d0.x + h0.y * d0.y + h0.z * d0.z + h0.w * d0.w
            + h1.x * d1.x + h1.y * d1.y + h1.z * d1.z + h1.w * d1.w;
    for (int m = 8; m >= 1; m >>= 1) {
      s += __shfl_xor(s, m, 16);
      d += __shfl_xor(d, m, 16);
    }
    if (l == 0) {
      a_src_sm[n] = s;
      a_dst_sm[n] = d;
    }
  }
  __syncthreads();

  // --- phase 2: w[i][j] = sigmoid(leaky_relu(a_src[j] + a_dst[i], 0.01)) ---
  {
    const int i = tid >> 4, j = tid & 15;
    float e = a_src_sm[j] + a_dst_sm[i];
    e = (e >= 0.f) ? e : 0.01f * e;
    const float wv = 1.f / (1.f + expf(-e));
    w_sm[tid] = wv;
    __builtin_nontemporal_store(wv, &out_w[(size_t)b * 256 + tid]);  // output 1
  }
  __syncthreads();

  // --- phase 3a: sum_z[i][a] = sum_j (w[i][j]*act[j][a] + (1-w)*pol[j][a]) ---
  if (tid < 128) {
    const int i = tid >> 3, a = tid & 7;
    float s = 0.f;
    for (int j = 0; j < N_SZ; ++j) {
      const float wv = w_sm[i * 16 + j];
      s += wv * act_sm[j * 8 + a] + (1.f - wv) * pol_sm[j * 8 + a];
    }
    sumz_sm[tid] = s;
  }
  __syncthreads();

  // --- phase 3b: out_z[i][k][a] = (sum_z[i][a] - zg[i][k][a] + pol[k][a])/16 ---
  {
    const int i = tid >> 4, k = tid & 15;
    const float wv = w_sm[tid];   // w[i][k]
    for (int a = 0; a < A_SZ; ++a) {
      const float zg = wv * act_sm[k * 8 + a] + (1.f - wv) * pol_sm[k * 8 + a];
      outz_sm[tid * 8 + a] =
          (sumz_sm[i * 8 + a] - zg + pol_sm[k * 8 + a]) * 0.0625f;
    }
  }
  __syncthreads();

  // --- phase 4: write 256 rows x 34 x 16B (fully contiguous per block) ---
  // flat 16B idx: r = idx/34, d4 = idx%34.
  // d4 < 32  -> obs_sm[k][d4*4 ..] ; d4 >= 32 -> outz_sm[r*8 + (d4-32)*4 ..]
  float* ob = out_obs + (size_t)b * (256 * ROW_OUT);
  const f32x4* obs4 = (const f32x4*)obs_sm;
  #pragma unroll 2
  for (int idx = tid; idx < 256 * 34; idx += 256) {
    const int r = idx / 34;
    const int d4 = idx - r * 34;
    f32x4 o4;
    if (d4 < 32) {
      const int k = r & 15;
      o4 = obs4[k * 32 + d4];
    } else {
      o4 = *(const f32x4*)(outz_sm + r * 8 + (d4 - 32) * 4);
    }
    __builtin_nontemporal_store(o4, (f32x4*)(ob + (size_t)idx * 4));
  }
}

// ---------------------------------------------------------------------------
extern "C" void kernel_launch(void* const* d_in, const int* in_sizes, int n_in,
                              void* d_out, int out_size, void* d_ws, size_t ws_size,
                              hipStream_t stream) {
  const float* h      = (const float*)d_in[0];
  const float* pol    = (const float*)d_in[1];
  const float* act    = (const float*)d_in[2];
  const float* obs    = (const float*)d_in[3];
  const float* W_fc   = (const float*)d_in[4];
  const float* W_attn = (const float*)d_in[5];

  float* out = (float*)d_out;
  float* out_w = out + (size_t)B_SZ * N_SZ * N_SZ * ROW_OUT;  // 142,606,336
  float* v = (float*)d_ws;  // 256 floats

  prep_v<<<1, 256, 0, stream>>>(W_fc, W_attn, v);
  gat_main<<<B_SZ, 256, 0, stream>>>(h, pol, act, obs, v, out, out_w);
}